// Round 9
// baseline (1122.135 us; speedup 1.0000x reference)
//
#include <hip/hip_runtime.h>

#define CIN    32
#define COUT   32
#define SCAN_B 2048
#define CH     256          // output rows per chunk (LDS accum = 32 KB)
#define MT     512          // main kernel block threads (8 waves)

typedef _Float16 h2_t __attribute__((ext_vector_type(2)));

__device__ __forceinline__ float dot2(unsigned f, unsigned w, float a)
{
#if __has_builtin(__builtin_amdgcn_fdot2)
    return __builtin_amdgcn_fdot2(__builtin_bit_cast(h2_t, f),
                                  __builtin_bit_cast(h2_t, w), a, false);
#else
    h2_t ff = __builtin_bit_cast(h2_t, f), ww = __builtin_bit_cast(h2_t, w);
    return a + (float)ff.x * (float)ww.x + (float)ff.y * (float)ww.y;
#endif
}

__device__ __forceinline__ unsigned f2h2(float a, float b)
{
    unsigned short ua = __builtin_bit_cast(unsigned short, (_Float16)a);
    unsigned short ub = __builtin_bit_cast(unsigned short, (_Float16)b);
    return (unsigned)ua | ((unsigned)ub << 16);
}

// ---- weights: wH2[((k*2+h)*8+j)*32+o] = f16pair(W[k][h*16+2j][o], W[k][h*16+2j+1][o])
__global__ void kb_pack2(const float* __restrict__ w, unsigned* __restrict__ wH2, int total)
{
    int idx = blockIdx.x * blockDim.x + threadIdx.x;
    if (idx >= total) return;
    int o = idx & 31, j = (idx >> 5) & 7, h = (idx >> 8) & 1, k = idx >> 9;
    int i0 = h * 16 + 2 * j;
    wH2[idx] = f2h2(w[(k * CIN + i0) * COUT + o], w[(k * CIN + i0 + 1) * COUT + o]);
}

// ---- features: fH[g*16+c] = f16pair(feat[g][2c], feat[g][2c+1]) ----
__global__ void kf_pack(const float* __restrict__ f, unsigned* __restrict__ fH, int total4)
{
    int idx = blockIdx.x * blockDim.x + threadIdx.x;
    if (idx >= total4) return;
    float4 v = ((const float4*)f)[idx];
    uint2 r; r.x = f2h2(v.x, v.y); r.y = f2h2(v.z, v.w);
    ((uint2*)fH)[idx] = r;
}

// ---- histogram per (chunk,k) bin ----
__global__ void kb_hist(const int* __restrict__ scatter, int* __restrict__ cnt,
                        int npair, int M, int K, int vec_ok)
{
    int k = blockIdx.y;
    const int* sp = scatter + (size_t)k * npair;
    int t = blockIdx.x * blockDim.x + threadIdx.x;
    if (vec_ok) {
        int base = t * 4;
        if (base >= npair) return;
        int4 s4 = *(const int4*)(sp + base);
        if (s4.x < M) atomicAdd(&cnt[(s4.x >> 8) * K + k], 1);
        if (s4.y < M) atomicAdd(&cnt[(s4.y >> 8) * K + k], 1);
        if (s4.z < M) atomicAdd(&cnt[(s4.z >> 8) * K + k], 1);
        if (s4.w < M) atomicAdd(&cnt[(s4.w >> 8) * K + k], 1);
    } else {
        if (t >= npair) return;
        int s = sp[t];
        if (s < M) atomicAdd(&cnt[(s >> 8) * K + k], 1);
    }
}

// ---- scan over int array: 3 phases ----
__global__ void sc1(const int* __restrict__ in, int* __restrict__ part, int n)
{
    __shared__ int red[256];
    int base = blockIdx.x * SCAN_B;
    int sum = 0;
    for (int i = threadIdx.x; i < SCAN_B; i += 256) {
        int idx = base + i;
        sum += (idx < n) ? in[idx] : 0;
    }
    red[threadIdx.x] = sum;
    __syncthreads();
    for (int s = 128; s > 0; s >>= 1) {
        if (threadIdx.x < s) red[threadIdx.x] += red[threadIdx.x + s];
        __syncthreads();
    }
    if (threadIdx.x == 0) part[blockIdx.x] = red[0];
}

__global__ void sc2(int* __restrict__ part, int nb, int* __restrict__ total_out)
{
    __shared__ int a[2048], b[2048];
    int t = threadIdx.x;
    for (int i = t; i < 2048; i += 1024) a[i] = (i < nb) ? part[i] : 0;
    __syncthreads();
    int* src = a; int* dst = b;
    for (int ofs = 1; ofs < 2048; ofs <<= 1) {
        for (int i = t; i < 2048; i += 1024)
            dst[i] = (i >= ofs) ? src[i] + src[i - ofs] : src[i];
        __syncthreads();
        int* tmp = src; src = dst; dst = tmp;
    }
    for (int i = t; i < 2048; i += 1024)
        if (i < nb) part[i] = (i == 0) ? 0 : src[i - 1];
    if (t == 0) *total_out = src[nb - 1];
}

__global__ void sc3(const int* __restrict__ in, const int* __restrict__ part,
                    int* __restrict__ outExcl, int n)
{
    __shared__ int ts[256];
    int base = blockIdx.x * SCAN_B;
    int v[8];
    int sum = 0;
#pragma unroll
    for (int j = 0; j < 8; ++j) {
        int idx = base + threadIdx.x * 8 + j;
        v[j] = (idx < n) ? in[idx] : 0;
        sum += v[j];
    }
    ts[threadIdx.x] = sum;
    __syncthreads();
    for (int ofs = 1; ofs < 256; ofs <<= 1) {
        int add = (threadIdx.x >= ofs) ? ts[threadIdx.x - ofs] : 0;
        __syncthreads();
        ts[threadIdx.x] += add;
        __syncthreads();
    }
    int excl = (threadIdx.x == 0) ? 0 : ts[threadIdx.x - 1];
    excl += part[blockIdx.x];
#pragma unroll
    for (int j = 0; j < 8; ++j) {
        int idx = base + threadIdx.x * 8 + j;
        if (idx < n) outExcl[idx] = excl;
        excl += v[j];
    }
}

// ---- scatter entries into (chunk,k) buckets: entry = (row_local<<18)|g ----
__global__ void kb_build2(const int* __restrict__ gather, const int* __restrict__ scatter,
                          const int* __restrict__ bin_start, int* __restrict__ cursor,
                          int* __restrict__ list, int npair, int M, int K, int vec_ok)
{
    int k = blockIdx.y;
    const int* sp = scatter + (size_t)k * npair;
    const int* gp = gather  + (size_t)k * npair;
    int t = blockIdx.x * blockDim.x + threadIdx.x;
    if (vec_ok) {
        int base = t * 4;
        if (base >= npair) return;
        int4 s4 = *(const int4*)(sp + base);
        int4 g4 = *(const int4*)(gp + base);
        if (s4.x < M) { int b = (s4.x >> 8) * K + k;
            list[bin_start[b] + atomicAdd(&cursor[b], 1)] = ((s4.x & 255) << 18) | g4.x; }
        if (s4.y < M) { int b = (s4.y >> 8) * K + k;
            list[bin_start[b] + atomicAdd(&cursor[b], 1)] = ((s4.y & 255) << 18) | g4.y; }
        if (s4.z < M) { int b = (s4.z >> 8) * K + k;
            list[bin_start[b] + atomicAdd(&cursor[b], 1)] = ((s4.z & 255) << 18) | g4.z; }
        if (s4.w < M) { int b = (s4.w >> 8) * K + k;
            list[bin_start[b] + atomicAdd(&cursor[b], 1)] = ((s4.w & 255) << 18) | g4.w; }
    } else {
        if (t >= npair) return;
        int s = sp[t];
        if (s < M) { int b = (s >> 8) * K + k;
            list[bin_start[b] + atomicAdd(&cursor[b], 1)] = ((s & 255) << 18) | gp[t]; }
    }
}

// ---- main: block per 256-row chunk; waves grab k-buckets; W[k] in VGPRs;
//      LDS f32 atomic accumulation; one coalesced write per chunk ----
__global__ __launch_bounds__(MT)
void kc_main(const unsigned* __restrict__ fH, const unsigned* __restrict__ wH2,
             const int* __restrict__ bin_start, const int* __restrict__ list,
             float* __restrict__ out, int M, int K)
{
    __shared__ float accS[CH * 32];     // 32 KB
    __shared__ int sBkt;
    const int c   = blockIdx.x;
    const int tid = threadIdx.x;

    for (int i = tid; i < CH * 32 / 4; i += MT)
        ((float4*)accS)[i] = make_float4(0.f, 0.f, 0.f, 0.f);
    if (tid == 0) sBkt = 0;
    __syncthreads();

    const int lane = tid & 63;
    const int o    = lane & 31;          // output channel
    const int h    = (lane >> 5) & 1;    // cin half (0: ch 0-15, 1: ch 16-31)

    for (;;) {
        int b;
        if (lane == 0) b = atomicAdd(&sBkt, 1);
        b = __shfl(b, 0, 64);
        if (b >= K) break;
        const int bin = c * K + b;
        int e0 = bin_start[bin], e1 = bin_start[bin + 1];
        if (e0 >= e1) continue;

        // this k's weight slice in registers: 8 f16-pairs per lane
        unsigned wr[8];
        const unsigned* wb = wH2 + ((b * 2 + h) * 8) * 32 + o;
#pragma unroll
        for (int j = 0; j < 8; ++j) wr[j] = wb[j * 32];

        // 2-stage pipeline over bucket entries
        int pkA = list[e0];
        uint4 fA0, fA1;
        {
            int g = pkA & 0x3FFFF; const unsigned* fb = fH + g * 16 + h * 8;
            fA0 = *(const uint4*)fb; fA1 = *(const uint4*)(fb + 4);
        }
        for (int e = e0; e < e1; ++e) {
            int pkB = 0; uint4 fB0, fB1;
            if (e + 1 < e1) {
                pkB = list[e + 1];
                int g = pkB & 0x3FFFF; const unsigned* fb = fH + g * 16 + h * 8;
                fB0 = *(const uint4*)fb; fB1 = *(const uint4*)(fb + 4);
            }
            float s = 0.f;
            s = dot2(fA0.x, wr[0], s); s = dot2(fA0.y, wr[1], s);
            s = dot2(fA0.z, wr[2], s); s = dot2(fA0.w, wr[3], s);
            s = dot2(fA1.x, wr[4], s); s = dot2(fA1.y, wr[5], s);
            s = dot2(fA1.z, wr[6], s); s = dot2(fA1.w, wr[7], s);
            s += __shfl_xor(s, 32, 64);          // combine cin halves
            int rl = pkA >> 18;
            if (lane < 32) atomicAdd(&accS[rl * 32 + o], s);   // ds_add_f32
            pkA = pkB; fA0 = fB0; fA1 = fB1;
        }
    }
    __syncthreads();

    // coalesced write-once output (no global memset needed)
    const int m0 = c * CH;
    int nrow = M - m0; if (nrow > CH) nrow = CH;
    float4* dst = (float4*)(out + (size_t)m0 * 32);
    for (int i = tid; i < nrow * 8; i += MT) dst[i] = ((const float4*)accS)[i];
}

// ---- fallback: atomic scatter (R1) ----
__global__ __launch_bounds__(256, 4)
void spconv_scatter(const float* __restrict__ feat, const float* __restrict__ weight,
                    const int* __restrict__ gather, const int* __restrict__ scatter,
                    float* __restrict__ out, int npair, int M)
{
    const int k = blockIdx.y;
    const int lane = threadIdx.x & 31;
    const int sub = threadIdx.x >> 5;
    const int pairs_per_blk = blockDim.x >> 5;
    const float* wk = weight + (size_t)k * (CIN * COUT);
    float w[CIN];
#pragma unroll
    for (int i = 0; i < CIN; ++i) w[i] = wk[i * COUT + lane];
    const int* gk = gather + (size_t)k * npair;
    const int* sk = scatter + (size_t)k * npair;
    for (int p = blockIdx.x * pairs_per_blk + sub; p < npair; p += gridDim.x * pairs_per_blk) {
        int s = sk[p];
        if (s >= M) continue;
        int g = gk[p];
        const float4* fr = (const float4*)(feat + (size_t)g * CIN);
        float a = 0.f;
#pragma unroll
        for (int c = 0; c < 8; ++c) {
            float4 f4 = fr[c];
            a = fmaf(f4.x, w[4*c+0], a); a = fmaf(f4.y, w[4*c+1], a);
            a = fmaf(f4.z, w[4*c+2], a); a = fmaf(f4.w, w[4*c+3], a);
        }
        atomicAdd(&out[(size_t)s * COUT + lane], a);
    }
}

extern "C" void kernel_launch(void* const* d_in, const int* in_sizes, int n_in,
                              void* d_out, int out_size, void* d_ws, size_t ws_size,
                              hipStream_t stream)
{
    const float* feat    = (const float*)d_in[0];
    const float* weight  = (const float*)d_in[1];
    const int*   gather  = (const int*)d_in[2];
    const int*   scatter = (const int*)d_in[3];
    float*       out     = (float*)d_out;

    const int N     = in_sizes[0] / CIN;            // input sites (150000)
    const int K     = in_sizes[1] / (CIN * COUT);   // 27
    const int npair = in_sizes[2] / K;              // 150000
    const int M     = out_size / COUT;              // num_out (~2.13M)
    const int NC    = (M + CH - 1) / CH;            // chunks (~8333)
    const int NBIN  = NC * K;                       // bins (~225K)
    const int NB    = (NBIN + SCAN_B - 1) / SCAN_B; // scan blocks (~110)

    // workspace: cnt | cursor | bin_start | part | wH2 | fH | list
    uintptr_t base = (uintptr_t)d_ws;
    auto align16 = [](uintptr_t p) { return (p + 15) & ~(uintptr_t)15; };
    uintptr_t p_cnt  = align16(base);                               // NBIN ints
    uintptr_t p_cur  = align16(p_cnt + (size_t)NBIN * 4);           // NBIN ints
    uintptr_t p_bs   = align16(p_cur + (size_t)NBIN * 4);           // NBIN+1 ints
    uintptr_t p_part = align16(p_bs + ((size_t)NBIN + 1) * 4);      // 2048 ints
    uintptr_t p_wH   = align16(p_part + 2048 * 4);                  // K*512 uints
    uintptr_t p_fH   = align16(p_wH + (size_t)K * 512 * 4);         // N*16 uints
    uintptr_t p_list = align16(p_fH + (size_t)N * 16 * 4);          // K*npair ints
    uintptr_t p_end  = p_list + (size_t)K * npair * 4;

    if (p_end - base > ws_size || NB > 2048 || N > 0x3FFFF) {
        hipMemsetAsync(d_out, 0, (size_t)out_size * sizeof(float), stream);
        dim3 grid(160, K);
        spconv_scatter<<<grid, 256, 0, stream>>>(feat, weight, gather, scatter, out, npair, M);
        return;
    }

    int*      cnt  = (int*)p_cnt;
    int*      cur  = (int*)p_cur;
    int*      bs   = (int*)p_bs;
    int*      part = (int*)p_part;
    unsigned* wH2  = (unsigned*)p_wH;
    unsigned* fH   = (unsigned*)p_fH;
    int*      list = (int*)p_list;

    const int vec_ok = ((npair & 3) == 0) ? 1 : 0;

    hipMemsetAsync(cnt, 0, (size_t)NBIN * 4, stream);
    hipMemsetAsync(cur, 0, (size_t)NBIN * 4, stream);

    kb_pack2<<<(K * 512 + 255) / 256, 256, 0, stream>>>(weight, wH2, K * 512);
    kf_pack<<<(N * 8 + 255) / 256, 256, 0, stream>>>(feat, fH, N * 8);

    const int pthreads = vec_ok ? npair / 4 : npair;
    dim3 gp((pthreads + 255) / 256, K);
    kb_hist<<<gp, 256, 0, stream>>>(scatter, cnt, npair, M, K, vec_ok);

    sc1<<<NB, 256, 0, stream>>>(cnt, part, NBIN);
    sc2<<<1, 1024, 0, stream>>>(part, NB, bs + NBIN);   // total -> bs[NBIN]
    sc3<<<NB, 256, 0, stream>>>(cnt, part, bs, NBIN);

    kb_build2<<<gp, 256, 0, stream>>>(gather, scatter, bs, cur, list, npair, M, K, vec_ok);

    kc_main<<<NC, MT, 0, stream>>>(fH, wH2, bs, list, out, M, K);
}

// Round 10
// 804.011 us; speedup vs baseline: 1.3957x; 1.3957x over previous
//
#include <hip/hip_runtime.h>

#define CIN    32
#define COUT   32
#define KMAX   27
#define SCAN_B 2048

typedef _Float16 h2_t __attribute__((ext_vector_type(2)));

__device__ __forceinline__ float dot2(unsigned f, unsigned w, float a)
{
#if __has_builtin(__builtin_amdgcn_fdot2)
    return __builtin_amdgcn_fdot2(__builtin_bit_cast(h2_t, f),
                                  __builtin_bit_cast(h2_t, w), a, false);
#else
    h2_t ff = __builtin_bit_cast(h2_t, f), ww = __builtin_bit_cast(h2_t, w);
    return a + (float)ff.x * (float)ww.x + (float)ff.y * (float)ww.y;
#endif
}

__device__ __forceinline__ unsigned f2h2(float a, float b)
{
    unsigned short ua = __builtin_bit_cast(unsigned short, (_Float16)a);
    unsigned short ub = __builtin_bit_cast(unsigned short, (_Float16)b);
    return (unsigned)ua | ((unsigned)ub << 16);
}

// ---- pack weights for wave64 layout:
//      uint idx = (((k*2+h)*2+jq)*32 + o)*4 + j4, j = jq*4+j4, i0 = h*16+2j
//      -> lane (o,h) reads 2 contiguous uint4 at consecutive-lane 16B stride
__global__ void kb_pack3(const float* __restrict__ w, unsigned* __restrict__ wH, int total)
{
    int idx = blockIdx.x * blockDim.x + threadIdx.x;
    if (idx >= total) return;
    int j4 = idx & 3, o = (idx >> 2) & 31, jq = (idx >> 7) & 1, h = (idx >> 8) & 1, k = idx >> 9;
    int j = jq * 4 + j4;
    int i0 = h * 16 + 2 * j;
    wH[idx] = f2h2(w[(k * CIN + i0) * COUT + o], w[(k * CIN + i0 + 1) * COUT + o]);
}

// ---- pack features: fH[g*16+c] = f16pair(feat[g][2c], feat[g][2c+1]) ----
__global__ void kf_pack(const float* __restrict__ f, unsigned* __restrict__ fH, int total4)
{
    int idx = blockIdx.x * blockDim.x + threadIdx.x;
    if (idx >= total4) return;
    float4 v = ((const float4*)f)[idx];
    uint2 r; r.x = f2h2(v.x, v.y); r.y = f2h2(v.z, v.w);
    ((uint2*)fH)[idx] = r;
}

// ---- per-row k-mask (injective within k => 1 bit per (row,k)) ----
__global__ void kb_mask(const int* __restrict__ scatter, unsigned* __restrict__ mask,
                        int npair, int M, int vec_ok)
{
    int k = blockIdx.y;
    const int* sp = scatter + (size_t)k * npair;
    int t = blockIdx.x * blockDim.x + threadIdx.x;
    if (vec_ok) {
        int base = t * 4;
        if (base >= npair) return;
        unsigned kb = 1u << k;
        int4 s4 = *(const int4*)(sp + base);
        if (s4.x < M) atomicOr(&mask[s4.x], kb);
        if (s4.y < M) atomicOr(&mask[s4.y], kb);
        if (s4.z < M) atomicOr(&mask[s4.z], kb);
        if (s4.w < M) atomicOr(&mask[s4.w], kb);
    } else {
        if (t >= npair) return;
        int s = sp[t];
        if (s < M) atomicOr(&mask[s], 1u << k);
    }
}

// ---- scan level 1: per-block sums of popcount(mask) ----
__global__ void kb_scan1(const unsigned* __restrict__ mask, int* __restrict__ part, int n)
{
    __shared__ int red[256];
    int base = blockIdx.x * SCAN_B;
    int sum = 0;
    for (int i = threadIdx.x; i < SCAN_B; i += 256) {
        int idx = base + i;
        sum += (idx < n) ? __popc(mask[idx]) : 0;
    }
    red[threadIdx.x] = sum;
    __syncthreads();
    for (int s = 128; s > 0; s >>= 1) {
        if (threadIdx.x < s) red[threadIdx.x] += red[threadIdx.x + s];
        __syncthreads();
    }
    if (threadIdx.x == 0) part[blockIdx.x] = red[0];
}

// ---- scan level 2: single-block exclusive scan of part[0..nb), nb<=2048 ----
__global__ void kb_scan2(int* __restrict__ part, int nb, int* __restrict__ total_out)
{
    __shared__ int a[2048], b[2048];
    int t = threadIdx.x;
    for (int i = t; i < 2048; i += 1024) a[i] = (i < nb) ? part[i] : 0;
    __syncthreads();
    int* src = a; int* dst = b;
    for (int ofs = 1; ofs < 2048; ofs <<= 1) {
        for (int i = t; i < 2048; i += 1024)
            dst[i] = (i >= ofs) ? src[i] + src[i - ofs] : src[i];
        __syncthreads();
        int* tmp = src; src = dst; dst = tmp;
    }
    for (int i = t; i < 2048; i += 1024)
        if (i < nb) part[i] = (i == 0) ? 0 : src[i - 1];
    if (t == 0) *total_out = src[nb - 1];
}

// ---- scan level 3: block-local exclusive scan of popcounts + block offset ----
__global__ void kb_scan3(const unsigned* __restrict__ mask, const int* __restrict__ part,
                         int* __restrict__ row_start, int n)
{
    __shared__ int ts[256];
    int base = blockIdx.x * SCAN_B;
    int v[8];
    int sum = 0;
#pragma unroll
    for (int j = 0; j < 8; ++j) {
        int idx = base + threadIdx.x * 8 + j;
        v[j] = (idx < n) ? __popc(mask[idx]) : 0;
        sum += v[j];
    }
    ts[threadIdx.x] = sum;
    __syncthreads();
    for (int ofs = 1; ofs < 256; ofs <<= 1) {
        int add = (threadIdx.x >= ofs) ? ts[threadIdx.x - ofs] : 0;
        __syncthreads();
        ts[threadIdx.x] += add;
        __syncthreads();
    }
    int excl = (threadIdx.x == 0) ? 0 : ts[threadIdx.x - 1];
    excl += part[blockIdx.x];
#pragma unroll
    for (int j = 0; j < 8; ++j) {
        int idx = base + threadIdx.x * 8 + j;
        if (idx < n) row_start[idx] = excl;
        excl += v[j];
    }
}

// ---- build CSR entries, slot deterministic (k-ascending within row) ----
__global__ void kb_build(const int* __restrict__ gather, const int* __restrict__ scatter,
                         const unsigned* __restrict__ mask, const int* __restrict__ row_start,
                         int* __restrict__ list, int npair, int M, int vec_ok)
{
    int k = blockIdx.y;
    const int* sp = scatter + (size_t)k * npair;
    const int* gp = gather  + (size_t)k * npair;
    unsigned klow = (1u << k) - 1u;
    int t = blockIdx.x * blockDim.x + threadIdx.x;
    if (vec_ok) {
        int base = t * 4;
        if (base >= npair) return;
        int4 s4 = *(const int4*)(sp + base);
        int4 g4 = *(const int4*)(gp + base);
        if (s4.x < M) list[row_start[s4.x] + __popc(mask[s4.x] & klow)] = (k << 18) | g4.x;
        if (s4.y < M) list[row_start[s4.y] + __popc(mask[s4.y] & klow)] = (k << 18) | g4.y;
        if (s4.z < M) list[row_start[s4.z] + __popc(mask[s4.z] & klow)] = (k << 18) | g4.z;
        if (s4.w < M) list[row_start[s4.w] + __popc(mask[s4.w] & klow)] = (k << 18) | g4.w;
    } else {
        if (t >= npair) return;
        int s = sp[t];
        if (s < M) list[row_start[s] + __popc(mask[s] & klow)] = (k << 18) | gp[t];
    }
}

// ---- main: ONE wave64 per output row. lane = (h, o): o = cout, h = cin half.
//      Per entry: uniform list load, 2 broadcast feat uint4 per half,
//      2 conflict-free ds_read_b128 of weights, 8 dot2, 1 shfl_xor combine.
//      Entry loop is wave-uniform -> zero divergence. Write-once output. ----
__global__ __launch_bounds__(1024, 8)
void kw_main(const unsigned* __restrict__ fH, const uint4* __restrict__ wH,
             const int* __restrict__ row_start, const int* __restrict__ list,
             float* __restrict__ out, int M, int K)
{
    __shared__ uint4 wL[KMAX * 128];     // [((k*2+h)*2+jq)*32+o] : 55296 B
    for (int i = threadIdx.x; i < K * 128; i += 1024) wL[i] = wH[i];
    __syncthreads();

    const int lane = threadIdx.x & 63;
    const int o    = lane & 31;          // output channel
    const int h    = lane >> 5;          // cin half

    int wid = (blockIdx.x * 1024 + threadIdx.x) >> 6;
    int nW  = (gridDim.x * 1024) >> 6;

    for (int m = wid; m < M; m += nW) {
        const int e0 = row_start[m], e1 = row_start[m + 1];
        float acc = 0.f;
        for (int e = e0; e < e1; ++e) {
            const int pk = list[e];                 // uniform (scalar) load
            const int k = pk >> 18, g = pk & 0x3FFFF;
            const uint4* fb = (const uint4*)(fH + g * 16 + h * 8);
            uint4 f0 = fb[0], f1 = fb[1];           // broadcast within half
            const uint4* wb = wL + ((k * 2 + h) * 2) * 32 + o;
            uint4 w0 = wb[0], w1 = wb[32];          // consecutive-lane 16B stride
            float s = 0.f;
            s = dot2(f0.x, w0.x, s); s = dot2(f0.y, w0.y, s);
            s = dot2(f0.z, w0.z, s); s = dot2(f0.w, w0.w, s);
            s = dot2(f1.x, w1.x, s); s = dot2(f1.y, w1.y, s);
            s = dot2(f1.z, w1.z, s); s = dot2(f1.w, w1.w, s);
            s += __shfl_xor(s, 32, 64);             // combine cin halves
            acc += s;
        }
        if (lane < 32) out[(size_t)m * COUT + o] = acc;
    }
}

// ---- fallback: atomic scatter (R1) ----
__global__ __launch_bounds__(256, 4)
void spconv_scatter(const float* __restrict__ feat, const float* __restrict__ weight,
                    const int* __restrict__ gather, const int* __restrict__ scatter,
                    float* __restrict__ out, int npair, int M)
{
    const int k = blockIdx.y;
    const int lane = threadIdx.x & 31;
    const int sub = threadIdx.x >> 5;
    const int pairs_per_blk = blockDim.x >> 5;
    const float* wk = weight + (size_t)k * (CIN * COUT);
    float w[CIN];
#pragma unroll
    for (int i = 0; i < CIN; ++i) w[i] = wk[i * COUT + lane];
    const int* gk = gather + (size_t)k * npair;
    const int* sk = scatter + (size_t)k * npair;
    for (int p = blockIdx.x * pairs_per_blk + sub; p < npair; p += gridDim.x * pairs_per_blk) {
        int s = sk[p];
        if (s >= M) continue;
        int g = gk[p];
        const float4* fr = (const float4*)(feat + (size_t)g * CIN);
        float a = 0.f;
#pragma unroll
        for (int c = 0; c < 8; ++c) {
            float4 f4 = fr[c];
            a = fmaf(f4.x, w[4*c+0], a); a = fmaf(f4.y, w[4*c+1], a);
            a = fmaf(f4.z, w[4*c+2], a); a = fmaf(f4.w, w[4*c+3], a);
        }
        atomicAdd(&out[(size_t)s * COUT + lane], a);
    }
}

extern "C" void kernel_launch(void* const* d_in, const int* in_sizes, int n_in,
                              void* d_out, int out_size, void* d_ws, size_t ws_size,
                              hipStream_t stream)
{
    const float* feat    = (const float*)d_in[0];
    const float* weight  = (const float*)d_in[1];
    const int*   gather  = (const int*)d_in[2];
    const int*   scatter = (const int*)d_in[3];
    float*       out     = (float*)d_out;

    const int N     = in_sizes[0] / CIN;            // input sites (150000)
    const int K     = in_sizes[1] / (CIN * COUT);   // 27
    const int npair = in_sizes[2] / K;              // 150000
    const int M     = out_size / COUT;              // num_out (~2.13M)
    const int NB    = (M + SCAN_B - 1) / SCAN_B;    // scan blocks (~1041)

    // workspace layout
    uintptr_t base = (uintptr_t)d_ws;
    auto align16 = [](uintptr_t p) { return (p + 15) & ~(uintptr_t)15; };
    uintptr_t p_mask = align16(base);                              // M uints
    uintptr_t p_rs   = align16(p_mask + (size_t)M * 4);            // M+1 ints
    uintptr_t p_part = align16(p_rs + ((size_t)M + 1) * 4);        // 2048 ints
    uintptr_t p_wH   = align16(p_part + 2048 * 4);                 // K*512 uints
    uintptr_t p_fH   = align16(p_wH + (size_t)K * 512 * 4);        // N*16 uints
    uintptr_t p_list = align16(p_fH + (size_t)N * 16 * 4);         // K*npair ints
    uintptr_t p_end  = p_list + (size_t)K * npair * 4;

    if (p_end - base > ws_size || NB > 2048 || K > KMAX || N > 0x40000) {
        hipMemsetAsync(d_out, 0, (size_t)out_size * sizeof(float), stream);
        dim3 grid(160, K);
        spconv_scatter<<<grid, 256, 0, stream>>>(feat, weight, gather, scatter, out, npair, M);
        return;
    }

    unsigned* mask      = (unsigned*)p_mask;
    int*      row_start = (int*)p_rs;
    int*      part      = (int*)p_part;
    unsigned* wH        = (unsigned*)p_wH;
    unsigned* fH        = (unsigned*)p_fH;
    int*      list      = (int*)p_list;

    const int vec_ok = ((npair & 3) == 0) ? 1 : 0;

    hipMemsetAsync(mask, 0, (size_t)M * 4, stream);

    kb_pack3<<<(K * 512 + 255) / 256, 256, 0, stream>>>(weight, wH, K * 512);
    kf_pack<<<(N * 8 + 255) / 256, 256, 0, stream>>>(feat, fH, N * 8);

    const int pthreads = vec_ok ? npair / 4 : npair;
    dim3 gp((pthreads + 255) / 256, K);
    kb_mask<<<gp, 256, 0, stream>>>(scatter, mask, npair, M, vec_ok);

    kb_scan1<<<NB, 256, 0, stream>>>(mask, part, M);
    kb_scan2<<<1, 1024, 0, stream>>>(part, NB, row_start + M);
    kb_scan3<<<NB, 256, 0, stream>>>(mask, part, row_start, M);

    kb_build<<<gp, 256, 0, stream>>>(gather, scatter, mask, row_start, list, npair, M, vec_ok);

    // write-once main: every output row covered, no memset of d_out
    kw_main<<<512, 1024, 0, stream>>>(fH, (const uint4*)wH, row_start, list, out, M, K);
}